// Round 1
// baseline (457.767 us; speedup 1.0000x reference)
//
#include <hip/hip_runtime.h>
#include <hip/hip_bf16.h>
#include <cmath>

#define B_ 4
#define S_ 2048
#define D_ 1024
#define H_ 16
#define DH_ 64

typedef __bf16 bf16_t;
typedef __bf16 bf16x8 __attribute__((ext_vector_type(8)));
typedef float f32x4 __attribute__((ext_vector_type(4)));

static __device__ __forceinline__ f32x4 mfma16(bf16x8 a, bf16x8 b, f32x4 c) {
    return __builtin_amdgcn_mfma_f32_16x16x32_bf16(a, b, c, 0, 0, 0);
}

// ---------------- RoPE sin/cos table: tab[s][i] = (sin, cos), i = 0..31 -------------
__global__ void rope_table_kernel(float2* __restrict__ tab) {
    int idx = blockIdx.x * 256 + threadIdx.x;       // 0 .. S_*32-1
    int s = idx >> 5, i = idx & 31;
    float inv = powf(10000.f, -(2.f * i) / 64.f);
    float ang = (float)s * inv;
    tab[idx] = make_float2(sinf(ang), cosf(ang));
}

// ---------------- Projection GEMM: dst = X @ W^T, fused head-split (+RoPE) ----------
// EPI 0: RoPE, write [B][H][S][DH] bf16   (q, k)
// EPI 1: no RoPE, write V^T [B][H][DH][S] bf16  (v)
template<int EPI>
__global__ __launch_bounds__(256)
void proj_kernel(const float* __restrict__ X, const float* __restrict__ W,
                 bf16_t* __restrict__ dst, const float2* __restrict__ tab)
{
    __shared__ bf16x8 lA[128 * 8];   // [row][k-chunk], chunk-XOR-swizzled
    __shared__ bf16x8 lB[128 * 8];
    const int tid = threadIdx.x;
    const int gm0 = blockIdx.x * 128;
    const int gn0 = blockIdx.y * 128;
    const int wid = tid >> 6, lane = tid & 63;
    const int lr = lane & 15, lh = lane >> 4;
    const int wm = (wid >> 1) * 64, wn = (wid & 1) * 64;

    f32x4 acc[4][4] = {};

    for (int kt = 0; kt < D_ / 64; ++kt) {
        const int k0 = kt * 64;
        __syncthreads();
        #pragma unroll
        for (int j = 0; j < 4; ++j) {
            int c = tid + 256 * j;
            int row = c >> 3, sl = c & 7;
            const float* pa = X + (size_t)(gm0 + row) * D_ + k0 + sl * 8;
            float4 a0 = *(const float4*)pa;
            float4 a1 = *(const float4*)(pa + 4);
            bf16x8 va = { (__bf16)a0.x, (__bf16)a0.y, (__bf16)a0.z, (__bf16)a0.w,
                          (__bf16)a1.x, (__bf16)a1.y, (__bf16)a1.z, (__bf16)a1.w };
            lA[row * 8 + (sl ^ (row & 7))] = va;
            const float* pb = W + (size_t)(gn0 + row) * D_ + k0 + sl * 8;
            float4 b0 = *(const float4*)pb;
            float4 b1 = *(const float4*)(pb + 4);
            bf16x8 vb = { (__bf16)b0.x, (__bf16)b0.y, (__bf16)b0.z, (__bf16)b0.w,
                          (__bf16)b1.x, (__bf16)b1.y, (__bf16)b1.z, (__bf16)b1.w };
            lB[row * 8 + (sl ^ (row & 7))] = vb;
        }
        __syncthreads();
        #pragma unroll
        for (int ks = 0; ks < 2; ++ks) {
            bf16x8 af[4], bfr[4];
            int kh = ks * 4 + lh;
            #pragma unroll
            for (int mi = 0; mi < 4; ++mi) { int r = wm + mi * 16 + lr; af[mi]  = lA[r * 8 + (kh ^ (r & 7))]; }
            #pragma unroll
            for (int ni = 0; ni < 4; ++ni) { int r = wn + ni * 16 + lr; bfr[ni] = lB[r * 8 + (kh ^ (r & 7))]; }
            #pragma unroll
            for (int mi = 0; mi < 4; ++mi)
                #pragma unroll
                for (int ni = 0; ni < 4; ++ni)
                    acc[mi][ni] = mfma16(af[mi], bfr[ni], acc[mi][ni]);
        }
    }

    // Epilogue. C/D layout: col = lane&15, row = (lane>>4)*4 + j
    #pragma unroll
    for (int mi = 0; mi < 4; ++mi) {
        #pragma unroll
        for (int j = 0; j < 4; ++j) {
            int m = gm0 + wm + mi * 16 + lh * 4 + j;   // b*S + s
            int b = m >> 11, s = m & (S_ - 1);
            #pragma unroll
            for (int ni = 0; ni < 4; ++ni) {
                int n = gn0 + wn + ni * 16 + lr;       // h*64 + dh
                int h = n >> 6, dh = n & 63;
                float x = acc[mi][ni][j];
                if (EPI == 0) {
                    float p = __shfl_xor(x, 1);        // partner column (adjacent lane)
                    float2 sc = tab[s * 32 + (dh >> 1)];
                    float r = (dh & 1) ? (p * sc.x + x * sc.y)   // odd:  x1*sin + x2*cos
                                       : (x * sc.y - p * sc.x);  // even: x1*cos - x2*sin
                    dst[(((size_t)b * H_ + h) * S_ + s) * DH_ + dh] = (bf16_t)r;
                } else {
                    dst[(((size_t)b * H_ + h) * DH_ + dh) * S_ + s] = (bf16_t)x;
                }
            }
        }
    }
}

// ---------------- Flash attention (causal), 4 waves x 32 q-rows, KBLK=64 ------------
__global__ __launch_bounds__(256)
void attn_kernel(const bf16_t* __restrict__ qh, const bf16_t* __restrict__ kh,
                 const bf16_t* __restrict__ vT, bf16_t* __restrict__ O)
{
    __shared__ bf16x8 lK[64 * 8];      // [krow][dh-chunk], swizzled
    __shared__ bf16x8 lV[64 * 8];      // [dh][kcol-chunk], swizzled
    __shared__ bf16x8 lP[4][32 * 8];   // per-wave P tile [32][64], swizzled
    const int tid = threadIdx.x, wid = tid >> 6, lane = tid & 63;
    const int lr = lane & 15, lh = lane >> 4;
    const int q0 = blockIdx.x * 128;
    const int bh = blockIdx.y;
    const bf16_t* Qp = qh + (size_t)bh * S_ * DH_;
    const bf16_t* Kp = kh + (size_t)bh * S_ * DH_;
    const bf16_t* Vp = vT + (size_t)bh * DH_ * S_;
    const int wq = q0 + wid * 32;

    bf16x8 qf[2][2];
    #pragma unroll
    for (int mi = 0; mi < 2; ++mi)
        #pragma unroll
        for (int ks = 0; ks < 2; ++ks)
            qf[mi][ks] = *(const bf16x8*)(Qp + (size_t)(wq + mi * 16 + lr) * DH_ + ks * 32 + lh * 8);

    f32x4 accO[2][4] = {};
    float mrun[2][4], lrun[2][4];
    #pragma unroll
    for (int mi = 0; mi < 2; ++mi)
        #pragma unroll
        for (int j = 0; j < 4; ++j) { mrun[mi][j] = -1e30f; lrun[mi][j] = 0.f; }

    const int nkt = q0 / 64 + 2;
    for (int kt = 0; kt < nkt; ++kt) {
        __syncthreads();
        #pragma unroll
        for (int j = 0; j < 2; ++j) {
            int c = tid + 256 * j;
            int row = c >> 3, sl = c & 7;
            lK[row * 8 + (sl ^ (row & 7))] = *(const bf16x8*)(Kp + (size_t)(kt * 64 + row) * DH_ + sl * 8);
            lV[row * 8 + (sl ^ (row & 7))] = *(const bf16x8*)(Vp + (size_t)row * S_ + kt * 64 + sl * 8);
        }
        __syncthreads();

        f32x4 sc[2][4] = {};
        #pragma unroll
        for (int ks = 0; ks < 2; ++ks) {
            bf16x8 kf[4];
            int kh8 = ks * 4 + lh;
            #pragma unroll
            for (int ni = 0; ni < 4; ++ni) { int r = ni * 16 + lr; kf[ni] = lK[r * 8 + (kh8 ^ (r & 7))]; }
            #pragma unroll
            for (int mi = 0; mi < 2; ++mi)
                #pragma unroll
                for (int ni = 0; ni < 4; ++ni)
                    sc[mi][ni] = mfma16(qf[mi][ks], kf[ni], sc[mi][ni]);
        }

        const bool needm = (kt * 64 + 63 > wq);
        #pragma unroll
        for (int mi = 0; mi < 2; ++mi) {
            #pragma unroll
            for (int j = 0; j < 4; ++j) {
                int qg = wq + mi * 16 + lh * 4 + j;
                float mx = -1e30f;
                #pragma unroll
                for (int ni = 0; ni < 4; ++ni) {
                    float v = sc[mi][ni][j] * 0.125f;
                    if (needm && (kt * 64 + ni * 16 + lr) > qg) v = -1e30f;
                    sc[mi][ni][j] = v;
                    mx = fmaxf(mx, v);
                }
                #pragma unroll
                for (int d = 1; d < 16; d <<= 1) mx = fmaxf(mx, __shfl_xor(mx, d));
                float mold = mrun[mi][j];
                float mnew = fmaxf(mold, mx);
                float rs = __expf(mold - mnew);
                mrun[mi][j] = mnew;
                float sum = 0.f;
                #pragma unroll
                for (int ni = 0; ni < 4; ++ni) {
                    float p = __expf(sc[mi][ni][j] - mnew);
                    sc[mi][ni][j] = p;
                    sum += p;
                }
                #pragma unroll
                for (int d = 1; d < 16; d <<= 1) sum += __shfl_xor(sum, d);
                lrun[mi][j] = lrun[mi][j] * rs + sum;
                #pragma unroll
                for (int ni = 0; ni < 4; ++ni) accO[mi][ni][j] *= rs;
                int prow = mi * 16 + lh * 4 + j;
                #pragma unroll
                for (int ni = 0; ni < 4; ++ni) {
                    int pcol = ni * 16 + lr;
                    ((bf16_t*)&lP[wid][prow * 8 + ((pcol >> 3) ^ (prow & 7))])[pcol & 7] =
                        (bf16_t)sc[mi][ni][j];
                }
            }
        }

        // PV: O += P @ V   (A = P from per-wave LDS, B = V^T tile)
        #pragma unroll
        for (int ks = 0; ks < 2; ++ks) {
            bf16x8 pf[2], vf[4];
            int kh8 = ks * 4 + lh;
            #pragma unroll
            for (int mi = 0; mi < 2; ++mi) { int r = mi * 16 + lr; pf[mi] = lP[wid][r * 8 + (kh8 ^ (r & 7))]; }
            #pragma unroll
            for (int ni = 0; ni < 4; ++ni) { int r = ni * 16 + lr; vf[ni] = lV[r * 8 + (kh8 ^ (r & 7))]; }
            #pragma unroll
            for (int mi = 0; mi < 2; ++mi)
                #pragma unroll
                for (int ni = 0; ni < 4; ++ni)
                    accO[mi][ni] = mfma16(pf[mi], vf[ni], accO[mi][ni]);
        }
    }

    int b = bh >> 4, h = bh & 15;
    #pragma unroll
    for (int mi = 0; mi < 2; ++mi) {
        #pragma unroll
        for (int j = 0; j < 4; ++j) {
            int s = wq + mi * 16 + lh * 4 + j;
            float inv = 1.f / lrun[mi][j];
            #pragma unroll
            for (int ni = 0; ni < 4; ++ni) {
                int dh = ni * 16 + lr;
                O[((size_t)(b * S_ + s)) * D_ + h * DH_ + dh] = (bf16_t)(accO[mi][ni][j] * inv);
            }
        }
    }
}

// ---------------- Output GEMM: out(f32) = O(bf16) @ Wo^T(f32->bf16) -----------------
__global__ __launch_bounds__(256)
void out_kernel(const bf16_t* __restrict__ A, const float* __restrict__ W,
                float* __restrict__ out)
{
    __shared__ bf16x8 lA[128 * 8];
    __shared__ bf16x8 lB[128 * 8];
    const int tid = threadIdx.x;
    const int gm0 = blockIdx.x * 128;
    const int gn0 = blockIdx.y * 128;
    const int wid = tid >> 6, lane = tid & 63;
    const int lr = lane & 15, lh = lane >> 4;
    const int wm = (wid >> 1) * 64, wn = (wid & 1) * 64;

    f32x4 acc[4][4] = {};

    for (int kt = 0; kt < D_ / 64; ++kt) {
        const int k0 = kt * 64;
        __syncthreads();
        #pragma unroll
        for (int j = 0; j < 4; ++j) {
            int c = tid + 256 * j;
            int row = c >> 3, sl = c & 7;
            lA[row * 8 + (sl ^ (row & 7))] =
                *(const bf16x8*)(A + (size_t)(gm0 + row) * D_ + k0 + sl * 8);
            const float* pb = W + (size_t)(gn0 + row) * D_ + k0 + sl * 8;
            float4 b0 = *(const float4*)pb;
            float4 b1 = *(const float4*)(pb + 4);
            bf16x8 vb = { (__bf16)b0.x, (__bf16)b0.y, (__bf16)b0.z, (__bf16)b0.w,
                          (__bf16)b1.x, (__bf16)b1.y, (__bf16)b1.z, (__bf16)b1.w };
            lB[row * 8 + (sl ^ (row & 7))] = vb;
        }
        __syncthreads();
        #pragma unroll
        for (int ks = 0; ks < 2; ++ks) {
            bf16x8 af[4], bfr[4];
            int kh = ks * 4 + lh;
            #pragma unroll
            for (int mi = 0; mi < 4; ++mi) { int r = wm + mi * 16 + lr; af[mi]  = lA[r * 8 + (kh ^ (r & 7))]; }
            #pragma unroll
            for (int ni = 0; ni < 4; ++ni) { int r = wn + ni * 16 + lr; bfr[ni] = lB[r * 8 + (kh ^ (r & 7))]; }
            #pragma unroll
            for (int mi = 0; mi < 4; ++mi)
                #pragma unroll
                for (int ni = 0; ni < 4; ++ni)
                    acc[mi][ni] = mfma16(af[mi], bfr[ni], acc[mi][ni]);
        }
    }

    #pragma unroll
    for (int mi = 0; mi < 4; ++mi)
        #pragma unroll
        for (int j = 0; j < 4; ++j) {
            int m = gm0 + wm + mi * 16 + lh * 4 + j;
            #pragma unroll
            for (int ni = 0; ni < 4; ++ni) {
                int n = gn0 + wn + ni * 16 + lr;
                out[(size_t)m * D_ + n] = acc[mi][ni][j];
            }
        }
}

extern "C" void kernel_launch(void* const* d_in, const int* in_sizes, int n_in,
                              void* d_out, int out_size, void* d_ws, size_t ws_size,
                              hipStream_t stream)
{
    const float* Q  = (const float*)d_in[0];
    const float* K  = (const float*)d_in[1];
    const float* V  = (const float*)d_in[2];
    const float* Wq = (const float*)d_in[3];
    const float* Wk = (const float*)d_in[4];
    const float* Wv = (const float*)d_in[5];
    const float* Wo = (const float*)d_in[6];
    float* out = (float*)d_out;

    char* ws = (char*)d_ws;
    const size_t MB = 1024 * 1024;
    bf16_t* qh = (bf16_t*)(ws);                 // [B][H][S][DH] bf16, 16 MB
    bf16_t* kh = (bf16_t*)(ws + 16 * MB);       // [B][H][S][DH] bf16, 16 MB
    bf16_t* vT = (bf16_t*)(ws + 32 * MB);       // [B][H][DH][S] bf16, 16 MB
    bf16_t* Ob = (bf16_t*)(ws + 48 * MB);       // [B*S][D] bf16, 16 MB
    float2* tab = (float2*)(ws + 64 * MB);      // [S][32] (sin,cos), 512 KB

    rope_table_kernel<<<S_ * 32 / 256, 256, 0, stream>>>(tab);

    dim3 g(64, 8);
    proj_kernel<0><<<g, 256, 0, stream>>>(Q, Wq, qh, tab);
    proj_kernel<0><<<g, 256, 0, stream>>>(K, Wk, kh, tab);
    proj_kernel<1><<<g, 256, 0, stream>>>(V, Wv, vT, tab);

    attn_kernel<<<dim3(S_ / 128, B_ * H_), 256, 0, stream>>>(qh, kh, vT, Ob);

    out_kernel<<<g, 256, 0, stream>>>(Ob, Wo, out);
}

// Round 3
// 242.531 us; speedup vs baseline: 1.8875x; 1.8875x over previous
//
#include <hip/hip_runtime.h>
#include <hip/hip_bf16.h>
#include <cmath>

#define B_ 4
#define S_ 2048
#define D_ 1024
#define H_ 16
#define DH_ 64

typedef __bf16 bf16_t;
typedef __bf16 bf16x8 __attribute__((ext_vector_type(8)));
typedef __bf16 bf16x4 __attribute__((ext_vector_type(4)));
typedef float f32x4 __attribute__((ext_vector_type(4)));

static __device__ __forceinline__ f32x4 mfma16(bf16x8 a, bf16x8 b, f32x4 c) {
    return __builtin_amdgcn_mfma_f32_16x16x32_bf16(a, b, c, 0, 0, 0);
}

// ---------------- RoPE sin/cos table: tab[s][i] = (sin, cos), i = 0..31 -------------
__global__ void rope_table_kernel(float2* __restrict__ tab) {
    int idx = blockIdx.x * 256 + threadIdx.x;       // 0 .. S_*32-1
    int s = idx >> 5, i = idx & 31;
    float inv = powf(10000.f, -(2.f * i) / 64.f);
    float ang = (float)s * inv;
    tab[idx] = make_float2(sinf(ang), cosf(ang));
}

// ---------------- Projection GEMM: dst = X @ W^T, fused head-split (+RoPE) ----------
template<int EPI>
__global__ __launch_bounds__(256)
void proj_kernel(const float* __restrict__ X, const float* __restrict__ W,
                 bf16_t* __restrict__ dst, const float2* __restrict__ tab)
{
    __shared__ bf16x8 lA[128 * 8];   // [row][k-chunk], chunk-XOR-swizzled
    __shared__ bf16x8 lB[128 * 8];
    const int tid = threadIdx.x;
    const int gm0 = blockIdx.x * 128;
    const int gn0 = blockIdx.y * 128;
    const int wid = tid >> 6, lane = tid & 63;
    const int lr = lane & 15, lh = lane >> 4;
    const int wm = (wid >> 1) * 64, wn = (wid & 1) * 64;

    f32x4 acc[4][4] = {};

    for (int kt = 0; kt < D_ / 64; ++kt) {
        const int k0 = kt * 64;
        __syncthreads();
        #pragma unroll
        for (int j = 0; j < 4; ++j) {
            int c = tid + 256 * j;
            int row = c >> 3, sl = c & 7;
            const float* pa = X + (size_t)(gm0 + row) * D_ + k0 + sl * 8;
            float4 a0 = *(const float4*)pa;
            float4 a1 = *(const float4*)(pa + 4);
            bf16x8 va = { (__bf16)a0.x, (__bf16)a0.y, (__bf16)a0.z, (__bf16)a0.w,
                          (__bf16)a1.x, (__bf16)a1.y, (__bf16)a1.z, (__bf16)a1.w };
            lA[row * 8 + (sl ^ (row & 7))] = va;
            const float* pb = W + (size_t)(gn0 + row) * D_ + k0 + sl * 8;
            float4 b0 = *(const float4*)pb;
            float4 b1 = *(const float4*)(pb + 4);
            bf16x8 vb = { (__bf16)b0.x, (__bf16)b0.y, (__bf16)b0.z, (__bf16)b0.w,
                          (__bf16)b1.x, (__bf16)b1.y, (__bf16)b1.z, (__bf16)b1.w };
            lB[row * 8 + (sl ^ (row & 7))] = vb;
        }
        __syncthreads();
        #pragma unroll
        for (int ks = 0; ks < 2; ++ks) {
            bf16x8 af[4], bfr[4];
            int kh = ks * 4 + lh;
            #pragma unroll
            for (int mi = 0; mi < 4; ++mi) { int r = wm + mi * 16 + lr; af[mi]  = lA[r * 8 + (kh ^ (r & 7))]; }
            #pragma unroll
            for (int ni = 0; ni < 4; ++ni) { int r = wn + ni * 16 + lr; bfr[ni] = lB[r * 8 + (kh ^ (r & 7))]; }
            #pragma unroll
            for (int mi = 0; mi < 4; ++mi)
                #pragma unroll
                for (int ni = 0; ni < 4; ++ni)
                    acc[mi][ni] = mfma16(af[mi], bfr[ni], acc[mi][ni]);
        }
    }

    // Epilogue. C/D layout: col = lane&15, row = (lane>>4)*4 + j
    #pragma unroll
    for (int mi = 0; mi < 4; ++mi) {
        #pragma unroll
        for (int j = 0; j < 4; ++j) {
            int m = gm0 + wm + mi * 16 + lh * 4 + j;   // b*S + s
            int b = m >> 11, s = m & (S_ - 1);
            #pragma unroll
            for (int ni = 0; ni < 4; ++ni) {
                int n = gn0 + wn + ni * 16 + lr;       // h*64 + dh
                int h = n >> 6, dh = n & 63;
                float x = acc[mi][ni][j];
                if (EPI == 0) {
                    float p = __shfl_xor(x, 1);        // partner column (adjacent lane)
                    float2 sc = tab[s * 32 + (dh >> 1)];
                    float r = (dh & 1) ? (p * sc.x + x * sc.y)   // odd:  x1*sin + x2*cos
                                       : (x * sc.y - p * sc.x);  // even: x1*cos - x2*sin
                    dst[(((size_t)b * H_ + h) * S_ + s) * DH_ + dh] = (bf16_t)r;
                } else {
                    dst[(((size_t)b * H_ + h) * DH_ + dh) * S_ + s] = (bf16_t)x;
                }
            }
        }
    }
}

// ---------------- Flash attention (causal), swapped-QK^T lane-parallel softmax ------
// 4 waves x 32 q-rows, KBLK=64. S^T = mfma(A=K, B=Q): lane owns q = 16*qi + (lane&15),
// holds 16 of its 64 kv scores; row reduce = in-lane tree + shfl_xor(16,32).
__global__ __launch_bounds__(256)
void attn_kernel(const bf16_t* __restrict__ qh, const bf16_t* __restrict__ kh,
                 const bf16_t* __restrict__ vT, bf16_t* __restrict__ O)
{
    __shared__ bf16x8 lK[64 * 8];      // [krow][dh-chunk], swizzled
    __shared__ bf16x8 lV[64 * 8];      // [dh][kcol-chunk], swizzled
    __shared__ bf16x8 lP4[4][256];     // per-wave P tile [32 q][64 kv] bf16, 16B-slot swizzled
    const int tid = threadIdx.x, wid = tid >> 6, lane = tid & 63;
    const int lr = lane & 15, lh = lane >> 4;
    // XCD swizzle: all 16 q-tiles of one bh land on same XCD (assuming xcd = bid % 8);
    // longest (largest q0) blocks first within each bh.
    const int bh = blockIdx.x & 63;
    const int q0 = (15 - (blockIdx.x >> 6)) * 128;
    const bf16_t* Qp = qh + (size_t)bh * S_ * DH_;
    const bf16_t* Kp = kh + (size_t)bh * S_ * DH_;
    const bf16_t* Vp = vT + (size_t)bh * DH_ * S_;
    const int wq = q0 + wid * 32;
    char* lP = (char*)lP4[wid];

    // Q fragments (B-operand of S^T), pre-scaled by 1/sqrt(DH) = 0.125
    bf16x8 qf[2][2];
    #pragma unroll
    for (int qi = 0; qi < 2; ++qi)
        #pragma unroll
        for (int ks = 0; ks < 2; ++ks) {
            bf16x8 t = *(const bf16x8*)(Qp + (size_t)(wq + qi * 16 + lr) * DH_ + ks * 32 + lh * 8);
            #pragma unroll
            for (int e = 0; e < 8; ++e) t[e] = (__bf16)((float)t[e] * 0.125f);
            qf[qi][ks] = t;
        }

    f32x4 accO[2][4] = {};
    float mrun[2] = { -1e30f, -1e30f };
    float lrun[2] = { 0.f, 0.f };

    const int nkt = q0 / 64 + 2;
    for (int kt = 0; kt < nkt; ++kt) {
        __syncthreads();
        #pragma unroll
        for (int j = 0; j < 2; ++j) {
            int c = tid + 256 * j;
            int row = c >> 3, sl = c & 7;
            lK[row * 8 + (sl ^ (row & 7))] = *(const bf16x8*)(Kp + (size_t)(kt * 64 + row) * DH_ + sl * 8);
            lV[row * 8 + (sl ^ (row & 7))] = *(const bf16x8*)(Vp + (size_t)row * S_ + kt * 64 + sl * 8);
        }
        __syncthreads();

        if (kt * 64 > wq + 31) continue;   // fully-masked tile for this wave (still did staging+syncs)

        // S^T = K·Q^T : sc[kvi][qi], row kv = 16*kvi + 4*lh + j, col q = 16*qi + lr
        f32x4 sc[4][2] = {};
        #pragma unroll
        for (int ks = 0; ks < 2; ++ks) {
            bf16x8 kf[4];
            int kh8 = ks * 4 + lh;
            #pragma unroll
            for (int kvi = 0; kvi < 4; ++kvi) { int r = kvi * 16 + lr; kf[kvi] = lK[r * 8 + (kh8 ^ (r & 7))]; }
            #pragma unroll
            for (int kvi = 0; kvi < 4; ++kvi)
                #pragma unroll
                for (int qi = 0; qi < 2; ++qi)
                    sc[kvi][qi] = mfma16(kf[kvi], qf[qi][ks], sc[kvi][qi]);
        }

        const bool needm = (kt * 64 + 63 > wq);
        const int kvb = kt * 64 + 4 * lh;
        float rs[2];
        #pragma unroll
        for (int qi = 0; qi < 2; ++qi) {
            const int qg = wq + qi * 16 + lr;
            float p[16];
            #pragma unroll
            for (int kvi = 0; kvi < 4; ++kvi)
                #pragma unroll
                for (int j = 0; j < 4; ++j) {
                    float x = sc[kvi][qi][j];
                    if (needm && (kvb + kvi * 16 + j) > qg) x = -1e30f;
                    p[kvi * 4 + j] = x;
                }
            // in-lane max tree (depth 4) + cross-group
            float m8[8], m4[4], m2[2];
            #pragma unroll
            for (int i = 0; i < 8; ++i) m8[i] = fmaxf(p[i], p[i + 8]);
            #pragma unroll
            for (int i = 0; i < 4; ++i) m4[i] = fmaxf(m8[i], m8[i + 4]);
            m2[0] = fmaxf(m4[0], m4[2]); m2[1] = fmaxf(m4[1], m4[3]);
            float mx = fmaxf(m2[0], m2[1]);
            mx = fmaxf(mx, __shfl_xor(mx, 16));
            mx = fmaxf(mx, __shfl_xor(mx, 32));
            float mold = mrun[qi];
            float mnew = fmaxf(mold, mx);
            rs[qi] = __expf(mold - mnew);
            mrun[qi] = mnew;
            // exp + sum
            #pragma unroll
            for (int i = 0; i < 16; ++i) p[i] = __expf(p[i] - mnew);
            float s8[8], s4[4];
            #pragma unroll
            for (int i = 0; i < 8; ++i) s8[i] = p[i] + p[i + 8];
            #pragma unroll
            for (int i = 0; i < 4; ++i) s4[i] = s8[i] + s8[i + 4];
            float sum = (s4[0] + s4[1]) + (s4[2] + s4[3]);
            sum += __shfl_xor(sum, 16);
            sum += __shfl_xor(sum, 32);
            lrun[qi] = lrun[qi] * rs[qi] + sum;
            // write P[q][kv] to per-wave LDS: 8B per kvi, 16B-slot XOR swizzle
            const int qhat = qi * 16 + lr;
            #pragma unroll
            for (int kvi = 0; kvi < 4; ++kvi) {
                bf16x4 h = { (__bf16)p[kvi * 4 + 0], (__bf16)p[kvi * 4 + 1],
                             (__bf16)p[kvi * 4 + 2], (__bf16)p[kvi * 4 + 3] };
                int slot = 2 * kvi + (lh >> 1);
                *(bf16x4*)(lP + qhat * 128 + ((slot ^ (qhat & 7)) * 16) + (lh & 1) * 8) = h;
            }
        }

        // rescale accO: rows q = 16*mi + 4*lh + j -> state lives at lane (4*lh + j)
        #pragma unroll
        for (int mi = 0; mi < 2; ++mi)
            #pragma unroll
            for (int j = 0; j < 4; ++j) {
                float r = __shfl(rs[mi], 4 * lh + j);
                #pragma unroll
                for (int ni = 0; ni < 4; ++ni) accO[mi][ni][j] *= r;
            }

        // PV: O += P @ V  (A = P from per-wave LDS, B = V^T tile)
        #pragma unroll
        for (int ks = 0; ks < 2; ++ks) {
            bf16x8 pf[2], vf[4];
            int kh8 = ks * 4 + lh;
            #pragma unroll
            for (int mi = 0; mi < 2; ++mi) {
                int row = mi * 16 + lr;
                int slot = 4 * ks + lh;
                pf[mi] = *(const bf16x8*)(lP + row * 128 + ((slot ^ (row & 7)) * 16));
            }
            #pragma unroll
            for (int ni = 0; ni < 4; ++ni) { int r = ni * 16 + lr; vf[ni] = lV[r * 8 + (kh8 ^ (r & 7))]; }
            #pragma unroll
            for (int mi = 0; mi < 2; ++mi)
                #pragma unroll
                for (int ni = 0; ni < 4; ++ni)
                    accO[mi][ni] = mfma16(pf[mi], vf[ni], accO[mi][ni]);
        }
    }

    int b = bh >> 4, h = bh & 15;
    #pragma unroll
    for (int mi = 0; mi < 2; ++mi) {
        #pragma unroll
        for (int j = 0; j < 4; ++j) {
            int s = wq + mi * 16 + lh * 4 + j;
            float inv = 1.f / __shfl(lrun[mi], 4 * lh + j);
            #pragma unroll
            for (int ni = 0; ni < 4; ++ni) {
                int dh = ni * 16 + lr;
                O[((size_t)(b * S_ + s)) * D_ + h * DH_ + dh] = (bf16_t)(accO[mi][ni][j] * inv);
            }
        }
    }
}

// ---------------- Output GEMM: out(f32) = O(bf16) @ Wo^T(f32->bf16) -----------------
__global__ __launch_bounds__(256)
void out_kernel(const bf16_t* __restrict__ A, const float* __restrict__ W,
                float* __restrict__ out)
{
    __shared__ bf16x8 lA[128 * 8];
    __shared__ bf16x8 lB[128 * 8];
    const int tid = threadIdx.x;
    const int gm0 = blockIdx.x * 128;
    const int gn0 = blockIdx.y * 128;
    const int wid = tid >> 6, lane = tid & 63;
    const int lr = lane & 15, lh = lane >> 4;
    const int wm = (wid >> 1) * 64, wn = (wid & 1) * 64;

    f32x4 acc[4][4] = {};

    for (int kt = 0; kt < D_ / 64; ++kt) {
        const int k0 = kt * 64;
        __syncthreads();
        #pragma unroll
        for (int j = 0; j < 4; ++j) {
            int c = tid + 256 * j;
            int row = c >> 3, sl = c & 7;
            lA[row * 8 + (sl ^ (row & 7))] =
                *(const bf16x8*)(A + (size_t)(gm0 + row) * D_ + k0 + sl * 8);
            const float* pb = W + (size_t)(gn0 + row) * D_ + k0 + sl * 8;
            float4 b0 = *(const float4*)pb;
            float4 b1 = *(const float4*)(pb + 4);
            bf16x8 vb = { (__bf16)b0.x, (__bf16)b0.y, (__bf16)b0.z, (__bf16)b0.w,
                          (__bf16)b1.x, (__bf16)b1.y, (__bf16)b1.z, (__bf16)b1.w };
            lB[row * 8 + (sl ^ (row & 7))] = vb;
        }
        __syncthreads();
        #pragma unroll
        for (int ks = 0; ks < 2; ++ks) {
            bf16x8 af[4], bfr[4];
            int kh = ks * 4 + lh;
            #pragma unroll
            for (int mi = 0; mi < 4; ++mi) { int r = wm + mi * 16 + lr; af[mi]  = lA[r * 8 + (kh ^ (r & 7))]; }
            #pragma unroll
            for (int ni = 0; ni < 4; ++ni) { int r = wn + ni * 16 + lr; bfr[ni] = lB[r * 8 + (kh ^ (r & 7))]; }
            #pragma unroll
            for (int mi = 0; mi < 4; ++mi)
                #pragma unroll
                for (int ni = 0; ni < 4; ++ni)
                    acc[mi][ni] = mfma16(af[mi], bfr[ni], acc[mi][ni]);
        }
    }

    #pragma unroll
    for (int mi = 0; mi < 4; ++mi)
        #pragma unroll
        for (int j = 0; j < 4; ++j) {
            int m = gm0 + wm + mi * 16 + lh * 4 + j;
            #pragma unroll
            for (int ni = 0; ni < 4; ++ni) {
                int n = gn0 + wn + ni * 16 + lr;
                out[(size_t)m * D_ + n] = acc[mi][ni][j];
            }
        }
}

extern "C" void kernel_launch(void* const* d_in, const int* in_sizes, int n_in,
                              void* d_out, int out_size, void* d_ws, size_t ws_size,
                              hipStream_t stream)
{
    const float* Q  = (const float*)d_in[0];
    const float* K  = (const float*)d_in[1];
    const float* V  = (const float*)d_in[2];
    const float* Wq = (const float*)d_in[3];
    const float* Wk = (const float*)d_in[4];
    const float* Wv = (const float*)d_in[5];
    const float* Wo = (const float*)d_in[6];
    float* out = (float*)d_out;

    char* ws = (char*)d_ws;
    const size_t MB = 1024 * 1024;
    bf16_t* qh = (bf16_t*)(ws);                 // [B][H][S][DH] bf16, 16 MB
    bf16_t* kh = (bf16_t*)(ws + 16 * MB);       // [B][H][S][DH] bf16, 16 MB
    bf16_t* vT = (bf16_t*)(ws + 32 * MB);       // [B][H][DH][S] bf16, 16 MB
    bf16_t* Ob = (bf16_t*)(ws + 48 * MB);       // [B*S][D] bf16, 16 MB
    float2* tab = (float2*)(ws + 64 * MB);      // [S][32] (sin,cos), 512 KB

    rope_table_kernel<<<S_ * 32 / 256, 256, 0, stream>>>(tab);

    dim3 g(64, 8);
    proj_kernel<0><<<g, 256, 0, stream>>>(Q, Wq, qh, tab);
    proj_kernel<0><<<g, 256, 0, stream>>>(K, Wk, kh, tab);
    proj_kernel<1><<<g, 256, 0, stream>>>(V, Wv, vT, tab);

    attn_kernel<<<1024, 256, 0, stream>>>(qh, kh, vT, Ob);

    out_kernel<<<g, 256, 0, stream>>>(Ob, Wo, out);
}

// Round 4
// 213.583 us; speedup vs baseline: 2.1433x; 1.1355x over previous
//
#include <hip/hip_runtime.h>
#include <hip/hip_bf16.h>
#include <cmath>

#define B_ 4
#define S_ 2048
#define D_ 1024
#define H_ 16
#define DH_ 64

typedef __bf16 bf16_t;
typedef __bf16 bf16x8 __attribute__((ext_vector_type(8)));
typedef __bf16 bf16x4 __attribute__((ext_vector_type(4)));
typedef float f32x4 __attribute__((ext_vector_type(4)));

static __device__ __forceinline__ f32x4 mfma16(bf16x8 a, bf16x8 b, f32x4 c) {
    return __builtin_amdgcn_mfma_f32_16x16x32_bf16(a, b, c, 0, 0, 0);
}

static __device__ __forceinline__ float fast_exp2(float x) {
#if __has_builtin(__builtin_amdgcn_exp2f)
    return __builtin_amdgcn_exp2f(x);
#else
    float r; asm("v_exp_f32 %0, %1" : "=v"(r) : "v"(x)); return r;
#endif
}

// ---------------- RoPE sin/cos table: tab[s][i] = (sin, cos), i = 0..31 -------------
__global__ void rope_table_kernel(float2* __restrict__ tab) {
    int idx = blockIdx.x * 256 + threadIdx.x;       // 0 .. S_*32-1
    int s = idx >> 5, i = idx & 31;
    float inv = powf(10000.f, -(2.f * i) / 64.f);
    float ang = (float)s * inv;
    tab[idx] = make_float2(sinf(ang), cosf(ang));
}

// ---------------- Projection GEMM: dst = X @ W^T, fused head-split (+RoPE) ----------
template<int EPI>
__global__ __launch_bounds__(256)
void proj_kernel(const float* __restrict__ X, const float* __restrict__ W,
                 bf16_t* __restrict__ dst, const float2* __restrict__ tab)
{
    __shared__ bf16x8 lA[128 * 8];   // [row][k-chunk], chunk-XOR-swizzled
    __shared__ bf16x8 lB[128 * 8];
    const int tid = threadIdx.x;
    const int gm0 = blockIdx.x * 128;
    const int gn0 = blockIdx.y * 128;
    const int wid = tid >> 6, lane = tid & 63;
    const int lr = lane & 15, lh = lane >> 4;
    const int wm = (wid >> 1) * 64, wn = (wid & 1) * 64;

    f32x4 acc[4][4] = {};

    for (int kt = 0; kt < D_ / 64; ++kt) {
        const int k0 = kt * 64;
        __syncthreads();
        #pragma unroll
        for (int j = 0; j < 4; ++j) {
            int c = tid + 256 * j;
            int row = c >> 3, sl = c & 7;
            const float* pa = X + (size_t)(gm0 + row) * D_ + k0 + sl * 8;
            float4 a0 = *(const float4*)pa;
            float4 a1 = *(const float4*)(pa + 4);
            bf16x8 va = { (__bf16)a0.x, (__bf16)a0.y, (__bf16)a0.z, (__bf16)a0.w,
                          (__bf16)a1.x, (__bf16)a1.y, (__bf16)a1.z, (__bf16)a1.w };
            lA[row * 8 + (sl ^ (row & 7))] = va;
            const float* pb = W + (size_t)(gn0 + row) * D_ + k0 + sl * 8;
            float4 b0 = *(const float4*)pb;
            float4 b1 = *(const float4*)(pb + 4);
            bf16x8 vb = { (__bf16)b0.x, (__bf16)b0.y, (__bf16)b0.z, (__bf16)b0.w,
                          (__bf16)b1.x, (__bf16)b1.y, (__bf16)b1.z, (__bf16)b1.w };
            lB[row * 8 + (sl ^ (row & 7))] = vb;
        }
        __syncthreads();
        #pragma unroll
        for (int ks = 0; ks < 2; ++ks) {
            bf16x8 af[4], bfr[4];
            int kh = ks * 4 + lh;
            #pragma unroll
            for (int mi = 0; mi < 4; ++mi) { int r = wm + mi * 16 + lr; af[mi]  = lA[r * 8 + (kh ^ (r & 7))]; }
            #pragma unroll
            for (int ni = 0; ni < 4; ++ni) { int r = wn + ni * 16 + lr; bfr[ni] = lB[r * 8 + (kh ^ (r & 7))]; }
            #pragma unroll
            for (int mi = 0; mi < 4; ++mi)
                #pragma unroll
                for (int ni = 0; ni < 4; ++ni)
                    acc[mi][ni] = mfma16(af[mi], bfr[ni], acc[mi][ni]);
        }
    }

    // Epilogue. C/D layout: col = lane&15, row = (lane>>4)*4 + j
    #pragma unroll
    for (int mi = 0; mi < 4; ++mi) {
        #pragma unroll
        for (int j = 0; j < 4; ++j) {
            int m = gm0 + wm + mi * 16 + lh * 4 + j;   // b*S + s
            int b = m >> 11, s = m & (S_ - 1);
            #pragma unroll
            for (int ni = 0; ni < 4; ++ni) {
                int n = gn0 + wn + ni * 16 + lr;       // h*64 + dh
                int h = n >> 6, dh = n & 63;
                float x = acc[mi][ni][j];
                if (EPI == 0) {
                    float p = __shfl_xor(x, 1);        // partner column (adjacent lane)
                    float2 sc = tab[s * 32 + (dh >> 1)];
                    float r = (dh & 1) ? (p * sc.x + x * sc.y)   // odd:  x1*sin + x2*cos
                                       : (x * sc.y - p * sc.x);  // even: x1*cos - x2*sin
                    dst[(((size_t)b * H_ + h) * S_ + s) * DH_ + dh] = (bf16_t)r;
                } else {
                    dst[(((size_t)b * H_ + h) * DH_ + dh) * S_ + s] = (bf16_t)x;
                }
            }
        }
    }
}

// ---------------- Flash attention (causal), balanced paired schedule ----------------
// 512 blocks x 8 waves x 16 q-rows. Block (bh, p) handles q-tiles (15-p) then p:
// total kv-tiles = 34 for every block -> zero tail imbalance.
// Swapped QK^T (S^T = K.Q^T): lane owns q-col = lane&15, 16 kv scores in-register.
// exp2-domain softmax (log2e folded into Q scale), defer-max rescale skip.
__global__ __launch_bounds__(512, 4)
void attn_kernel(const bf16_t* __restrict__ qh, const bf16_t* __restrict__ kh,
                 const bf16_t* __restrict__ vT, bf16_t* __restrict__ O)
{
    __shared__ bf16x8 lK[64 * 8];      // [krow][dh-chunk], swizzled
    __shared__ bf16x8 lV[64 * 8];      // [dh][kcol-chunk], swizzled
    __shared__ bf16x8 lP8[8][128];     // per-wave P tile [16 q][64 kv] bf16, swizzled
    const int tid = threadIdx.x, wid = tid >> 6, lane = tid & 63;
    const int lr = lane & 15, lh = lane >> 4;
    const int bh = blockIdx.x & 63;          // xcd = bid%8 = bh%8: q-tiles of one bh share XCD
    const int p  = blockIdx.x >> 6;          // 0..7
    const bf16_t* Qp = qh + (size_t)bh * S_ * DH_;
    const bf16_t* Kp = kh + (size_t)bh * S_ * DH_;
    const bf16_t* Vp = vT + (size_t)bh * DH_ * S_;
    char* lP = (char*)lP8[wid];
    const int b = bh >> 4, h = bh & 15;
    const float QSCALE = 0.125f * 1.44269504f;   // 1/sqrt(DH) * log2(e)

    #pragma unroll 1
    for (int ph = 0; ph < 2; ++ph) {
        const int q0 = (ph == 0 ? (15 - p) : p) * 128;
        const int wq = q0 + wid * 16;

        // Q fragments (B-operand of S^T), pre-scaled into log2 domain
        bf16x8 qf[2];
        #pragma unroll
        for (int ks = 0; ks < 2; ++ks) {
            bf16x8 t = *(const bf16x8*)(Qp + (size_t)(wq + lr) * DH_ + ks * 32 + lh * 8);
            #pragma unroll
            for (int e = 0; e < 8; ++e) t[e] = (__bf16)((float)t[e] * QSCALE);
            qf[ks] = t;
        }

        f32x4 accO[4] = {};
        float mrun = -1e30f, lrun = 0.f;
        const int nkt = q0 / 64 + 2;

        #pragma unroll 1
        for (int kt = 0; kt < nkt; ++kt) {
            __syncthreads();
            {   // 512 threads: one 16B chunk each of K and V
                int row = tid >> 3, sl = tid & 7;
                lK[row * 8 + (sl ^ (row & 7))] = *(const bf16x8*)(Kp + (size_t)(kt * 64 + row) * DH_ + sl * 8);
                lV[row * 8 + (sl ^ (row & 7))] = *(const bf16x8*)(Vp + (size_t)row * S_ + kt * 64 + sl * 8);
            }
            __syncthreads();

            if (kt * 64 > wq + 15) continue;   // fully-masked tile for this wave

            // S^T = K.Q^T : sc[kvi], kv row = 16*kvi + 4*lh + j, q col = lr
            f32x4 sc[4] = {};
            __builtin_amdgcn_s_setprio(1);
            #pragma unroll
            for (int ks = 0; ks < 2; ++ks) {
                int kh8 = ks * 4 + lh;
                #pragma unroll
                for (int kvi = 0; kvi < 4; ++kvi) {
                    int r = kvi * 16 + lr;
                    bf16x8 kf = lK[r * 8 + (kh8 ^ (r & 7))];
                    sc[kvi] = mfma16(kf, qf[ks], sc[kvi]);
                }
            }
            __builtin_amdgcn_s_setprio(0);

            const bool needm = (kt * 64 + 63 > wq);
            const int kvb = kt * 64 + 4 * lh;
            const int qg = wq + lr;
            float pv[16];
            #pragma unroll
            for (int kvi = 0; kvi < 4; ++kvi)
                #pragma unroll
                for (int j = 0; j < 4; ++j) {
                    float x = sc[kvi][j];
                    if (needm && (kvb + kvi * 16 + j) > qg) x = -1e30f;
                    pv[kvi * 4 + j] = x;
                }
            // row max: in-lane tree + cross-group
            float m8[8], m4v[4];
            #pragma unroll
            for (int i = 0; i < 8; ++i) m8[i] = fmaxf(pv[i], pv[i + 8]);
            #pragma unroll
            for (int i = 0; i < 4; ++i) m4v[i] = fmaxf(m8[i], m8[i + 4]);
            float mx = fmaxf(fmaxf(m4v[0], m4v[2]), fmaxf(m4v[1], m4v[3]));
            mx = fmaxf(mx, __shfl_xor(mx, 16));
            mx = fmaxf(mx, __shfl_xor(mx, 32));

            float mnew;
            float rs = 1.f;
            bool skip = __all(mx <= mrun + 8.0f);   // defer-max: P bounded by 2^8
            if (skip) {
                mnew = mrun;
            } else {
                mnew = fmaxf(mrun, mx);
                rs = fast_exp2(mrun - mnew);
                mrun = mnew;
            }
            // exp2 + sum
            #pragma unroll
            for (int i = 0; i < 16; ++i) pv[i] = fast_exp2(pv[i] - mnew);
            float s8[8], s4v[4];
            #pragma unroll
            for (int i = 0; i < 8; ++i) s8[i] = pv[i] + pv[i + 8];
            #pragma unroll
            for (int i = 0; i < 4; ++i) s4v[i] = s8[i] + s8[i + 4];
            float sum = (s4v[0] + s4v[1]) + (s4v[2] + s4v[3]);
            sum += __shfl_xor(sum, 16);
            sum += __shfl_xor(sum, 32);

            // write P[q][kv] to per-wave LDS: 8B per kvi, 16B-slot XOR swizzle
            #pragma unroll
            for (int kvi = 0; kvi < 4; ++kvi) {
                bf16x4 hv = { (__bf16)pv[kvi * 4 + 0], (__bf16)pv[kvi * 4 + 1],
                              (__bf16)pv[kvi * 4 + 2], (__bf16)pv[kvi * 4 + 3] };
                int slot = 2 * kvi + (lh >> 1);
                *(bf16x4*)(lP + lr * 128 + ((slot ^ (lr & 7)) * 16) + (lh & 1) * 8) = hv;
            }

            if (skip) {
                lrun += sum;
            } else {
                lrun = lrun * rs + sum;
                float r = __shfl(rs, 4 * lh + (0));
                // rescale accO rows q = 4*lh + j: state lives at lane (4*lh + j)
                #pragma unroll
                for (int j = 0; j < 4; ++j) {
                    float rj = __shfl(rs, 4 * lh + j);
                    #pragma unroll
                    for (int ni = 0; ni < 4; ++ni) accO[ni][j] *= rj;
                }
                (void)r;
            }

            // PV: O += P @ V  (A = P from per-wave LDS, B = V^T tile)
            __builtin_amdgcn_s_setprio(1);
            #pragma unroll
            for (int ks = 0; ks < 2; ++ks) {
                int kh8 = ks * 4 + lh;
                int slot = 4 * ks + lh;
                bf16x8 pf = *(const bf16x8*)(lP + lr * 128 + ((slot ^ (lr & 7)) * 16));
                #pragma unroll
                for (int ni = 0; ni < 4; ++ni) {
                    int r = ni * 16 + lr;
                    bf16x8 vf = lV[r * 8 + (kh8 ^ (r & 7))];
                    accO[ni] = mfma16(pf, vf, accO[ni]);
                }
            }
            __builtin_amdgcn_s_setprio(0);
        }

        // epilogue: rows q = 4*lh + j, col dh = ni*16 + lr
        #pragma unroll
        for (int j = 0; j < 4; ++j) {
            int s = wq + 4 * lh + j;
            float inv = 1.f / __shfl(lrun, 4 * lh + j);
            #pragma unroll
            for (int ni = 0; ni < 4; ++ni) {
                int dh = ni * 16 + lr;
                O[((size_t)(b * S_ + s)) * D_ + h * DH_ + dh] = (bf16_t)(accO[ni][j] * inv);
            }
        }
    }
}

// ---------------- Output GEMM: out(f32) = O(bf16) @ Wo^T(f32->bf16) -----------------
__global__ __launch_bounds__(256)
void out_kernel(const bf16_t* __restrict__ A, const float* __restrict__ W,
                float* __restrict__ out)
{
    __shared__ bf16x8 lA[128 * 8];
    __shared__ bf16x8 lB[128 * 8];
    const int tid = threadIdx.x;
    const int gm0 = blockIdx.x * 128;
    const int gn0 = blockIdx.y * 128;
    const int wid = tid >> 6, lane = tid & 63;
    const int lr = lane & 15, lh = lane >> 4;
    const int wm = (wid >> 1) * 64, wn = (wid & 1) * 64;

    f32x4 acc[4][4] = {};

    for (int kt = 0; kt < D_ / 64; ++kt) {
        const int k0 = kt * 64;
        __syncthreads();
        #pragma unroll
        for (int j = 0; j < 4; ++j) {
            int c = tid + 256 * j;
            int row = c >> 3, sl = c & 7;
            lA[row * 8 + (sl ^ (row & 7))] =
                *(const bf16x8*)(A + (size_t)(gm0 + row) * D_ + k0 + sl * 8);
            const float* pb = W + (size_t)(gn0 + row) * D_ + k0 + sl * 8;
            float4 b0 = *(const float4*)pb;
            float4 b1 = *(const float4*)(pb + 4);
            bf16x8 vb = { (__bf16)b0.x, (__bf16)b0.y, (__bf16)b0.z, (__bf16)b0.w,
                          (__bf16)b1.x, (__bf16)b1.y, (__bf16)b1.z, (__bf16)b1.w };
            lB[row * 8 + (sl ^ (row & 7))] = vb;
        }
        __syncthreads();
        #pragma unroll
        for (int ks = 0; ks < 2; ++ks) {
            bf16x8 af[4], bfr[4];
            int kh = ks * 4 + lh;
            #pragma unroll
            for (int mi = 0; mi < 4; ++mi) { int r = wm + mi * 16 + lr; af[mi]  = lA[r * 8 + (kh ^ (r & 7))]; }
            #pragma unroll
            for (int ni = 0; ni < 4; ++ni) { int r = wn + ni * 16 + lr; bfr[ni] = lB[r * 8 + (kh ^ (r & 7))]; }
            #pragma unroll
            for (int mi = 0; mi < 4; ++mi)
                #pragma unroll
                for (int ni = 0; ni < 4; ++ni)
                    acc[mi][ni] = mfma16(af[mi], bfr[ni], acc[mi][ni]);
        }
    }

    #pragma unroll
    for (int mi = 0; mi < 4; ++mi)
        #pragma unroll
        for (int j = 0; j < 4; ++j) {
            int m = gm0 + wm + mi * 16 + lh * 4 + j;
            #pragma unroll
            for (int ni = 0; ni < 4; ++ni) {
                int n = gn0 + wn + ni * 16 + lr;
                out[(size_t)m * D_ + n] = acc[mi][ni][j];
            }
        }
}

extern "C" void kernel_launch(void* const* d_in, const int* in_sizes, int n_in,
                              void* d_out, int out_size, void* d_ws, size_t ws_size,
                              hipStream_t stream)
{
    const float* Q  = (const float*)d_in[0];
    const float* K  = (const float*)d_in[1];
    const float* V  = (const float*)d_in[2];
    const float* Wq = (const float*)d_in[3];
    const float* Wk = (const float*)d_in[4];
    const float* Wv = (const float*)d_in[5];
    const float* Wo = (const float*)d_in[6];
    float* out = (float*)d_out;

    char* ws = (char*)d_ws;
    const size_t MB = 1024 * 1024;
    bf16_t* qh = (bf16_t*)(ws);                 // [B][H][S][DH] bf16, 16 MB
    bf16_t* kh = (bf16_t*)(ws + 16 * MB);       // [B][H][S][DH] bf16, 16 MB
    bf16_t* vT = (bf16_t*)(ws + 32 * MB);       // [B][H][DH][S] bf16, 16 MB
    bf16_t* Ob = (bf16_t*)(ws + 48 * MB);       // [B*S][D] bf16, 16 MB
    float2* tab = (float2*)(ws + 64 * MB);      // [S][32] (sin,cos), 512 KB

    rope_table_kernel<<<S_ * 32 / 256, 256, 0, stream>>>(tab);

    dim3 g(64, 8);
    proj_kernel<0><<<g, 256, 0, stream>>>(Q, Wq, qh, tab);
    proj_kernel<0><<<g, 256, 0, stream>>>(K, Wk, kh, tab);
    proj_kernel<1><<<g, 256, 0, stream>>>(V, Wv, vT, tab);

    attn_kernel<<<512, 512, 0, stream>>>(qh, kh, vT, Ob);

    out_kernel<<<g, 256, 0, stream>>>(Ob, Wo, out);
}

// Round 5
// 205.729 us; speedup vs baseline: 2.2251x; 1.0382x over previous
//
#include <hip/hip_runtime.h>
#include <hip/hip_bf16.h>
#include <cmath>

#define B_ 4
#define S_ 2048
#define D_ 1024
#define H_ 16
#define DH_ 64

typedef __bf16 bf16_t;
typedef __bf16 bf16x8 __attribute__((ext_vector_type(8)));
typedef __bf16 bf16x4 __attribute__((ext_vector_type(4)));
typedef float f32x4 __attribute__((ext_vector_type(4)));

static __device__ __forceinline__ f32x4 mfma16(bf16x8 a, bf16x8 b, f32x4 c) {
    return __builtin_amdgcn_mfma_f32_16x16x32_bf16(a, b, c, 0, 0, 0);
}

static __device__ __forceinline__ float fast_exp2(float x) {
#if __has_builtin(__builtin_amdgcn_exp2f)
    return __builtin_amdgcn_exp2f(x);
#else
    float r; asm("v_exp_f32 %0, %1" : "=v"(r) : "v"(x)); return r;
#endif
}

// async global->LDS, 16B per lane; lds dest must be wave-uniform (HW adds lane*16)
static __device__ __forceinline__ void glds16(const bf16_t* g, void* l) {
    __builtin_amdgcn_global_load_lds(
        (const __attribute__((address_space(1))) unsigned int*)g,
        (__attribute__((address_space(3))) unsigned int*)l, 16, 0, 0);
}

// ---------------- RoPE sin/cos table: tab[s][i] = (sin, cos), i = 0..31 -------------
__global__ void rope_table_kernel(float2* __restrict__ tab) {
    int idx = blockIdx.x * 256 + threadIdx.x;       // 0 .. S_*32-1
    int s = idx >> 5, i = idx & 31;
    float inv = powf(10000.f, -(2.f * i) / 64.f);
    float ang = (float)s * inv;
    tab[idx] = make_float2(sinf(ang), cosf(ang));
}

// ---------------- f32 -> bf16 convert (vectorized, 8 elems/thread) ------------------
__global__ __launch_bounds__(256)
void cvt_kernel(const float* __restrict__ src, bf16_t* __restrict__ dst) {
    int i = blockIdx.x * 256 + threadIdx.x;
    const float4* s = (const float4*)(src + (size_t)i * 8);
    float4 a = s[0], b = s[1];
    bf16x8 v = { (__bf16)a.x, (__bf16)a.y, (__bf16)a.z, (__bf16)a.w,
                 (__bf16)b.x, (__bf16)b.y, (__bf16)b.z, (__bf16)b.w };
    *(bf16x8*)(dst + (size_t)i * 8) = v;
}

// all four weight matrices in one launch: dst = 4 consecutive [1024*1024] bf16 arrays
__global__ __launch_bounds__(256)
void wcvt_kernel(const float* __restrict__ Wq, const float* __restrict__ Wk,
                 const float* __restrict__ Wv, const float* __restrict__ Wo,
                 bf16_t* __restrict__ dst) {
    int i = blockIdx.x * 256 + threadIdx.x;         // 0 .. 4*131072-1
    int t = i >> 17, j = i & 131071;
    const float* src = (t == 0) ? Wq : (t == 1) ? Wk : (t == 2) ? Wv : Wo;
    const float4* s = (const float4*)(src + (size_t)j * 8);
    float4 a = s[0], b = s[1];
    bf16x8 v = { (__bf16)a.x, (__bf16)a.y, (__bf16)a.z, (__bf16)a.w,
                 (__bf16)b.x, (__bf16)b.y, (__bf16)b.z, (__bf16)b.w };
    *(bf16x8*)(dst + (size_t)i * 8) = v;
}

// ---------------- Projection GEMM (bf16 in via global_load_lds) ---------------------
// dst = X @ W^T, fused head-split (+RoPE). EPI 0: RoPE -> [B][H][S][DH]; EPI 1: V^T.
// LDS slot (row, s) holds k-chunk c = s ^ (row&7)  (pre-swizzled global source).
template<int EPI>
__global__ __launch_bounds__(256)
void proj_kernel(const bf16_t* __restrict__ X, const bf16_t* __restrict__ W,
                 bf16_t* __restrict__ dst, const float2* __restrict__ tab)
{
    __shared__ bf16x8 lA[128 * 8];
    __shared__ bf16x8 lB[128 * 8];
    const int tid = threadIdx.x;
    const int gm0 = blockIdx.x * 128;
    const int gn0 = blockIdx.y * 128;
    const int wid = tid >> 6, lane = tid & 63;
    const int lr = lane & 15, lh = lane >> 4;
    const int wm = (wid >> 1) * 64, wn = (wid & 1) * 64;

    f32x4 acc[4][4] = {};

    for (int kt = 0; kt < D_ / 64; ++kt) {
        const int k0 = kt * 64;
        __syncthreads();
        #pragma unroll
        for (int i = 0; i < 4; ++i) {
            int base = wid * 64 + i * 256;
            int slot = base + lane;
            int row = slot >> 3, s = slot & 7, c = s ^ (row & 7);
            glds16(X + (size_t)(gm0 + row) * D_ + k0 + c * 8, &lA[base]);
            glds16(W + (size_t)(gn0 + row) * D_ + k0 + c * 8, &lB[base]);
        }
        __syncthreads();
        #pragma unroll
        for (int ks = 0; ks < 2; ++ks) {
            bf16x8 af[4], bfr[4];
            int kh = ks * 4 + lh;
            #pragma unroll
            for (int mi = 0; mi < 4; ++mi) { int r = wm + mi * 16 + lr; af[mi]  = lA[r * 8 + (kh ^ (r & 7))]; }
            #pragma unroll
            for (int ni = 0; ni < 4; ++ni) { int r = wn + ni * 16 + lr; bfr[ni] = lB[r * 8 + (kh ^ (r & 7))]; }
            #pragma unroll
            for (int mi = 0; mi < 4; ++mi)
                #pragma unroll
                for (int ni = 0; ni < 4; ++ni)
                    acc[mi][ni] = mfma16(af[mi], bfr[ni], acc[mi][ni]);
        }
    }

    // Epilogue. C/D layout: col = lane&15, row = (lane>>4)*4 + j
    #pragma unroll
    for (int mi = 0; mi < 4; ++mi) {
        #pragma unroll
        for (int j = 0; j < 4; ++j) {
            int m = gm0 + wm + mi * 16 + lh * 4 + j;   // b*S + s
            int b = m >> 11, s = m & (S_ - 1);
            #pragma unroll
            for (int ni = 0; ni < 4; ++ni) {
                int n = gn0 + wn + ni * 16 + lr;       // h*64 + dh
                int h = n >> 6, dh = n & 63;
                float x = acc[mi][ni][j];
                if (EPI == 0) {
                    float p = __shfl_xor(x, 1);        // partner column (adjacent lane)
                    float2 sc = tab[s * 32 + (dh >> 1)];
                    float r = (dh & 1) ? (p * sc.x + x * sc.y)   // odd:  x1*sin + x2*cos
                                       : (x * sc.y - p * sc.x);  // even: x1*cos - x2*sin
                    dst[(((size_t)b * H_ + h) * S_ + s) * DH_ + dh] = (bf16_t)r;
                } else {
                    dst[(((size_t)b * H_ + h) * DH_ + dh) * S_ + s] = (bf16_t)x;
                }
            }
        }
    }
}

// ---------------- Flash attention (causal), balanced paired schedule ----------------
// 512 blocks x 8 waves x 16 q-rows. Block (bh, p) handles q-tiles (15-p) then p:
// total kv-tiles = 34 for every block -> zero tail imbalance.
// Swapped QK^T (S^T = K.Q^T): lane owns q-col = lane&15, 16 kv scores in-register.
// exp2-domain softmax (log2e folded into Q scale), defer-max rescale skip.
__global__ __launch_bounds__(512, 4)
void attn_kernel(const bf16_t* __restrict__ qh, const bf16_t* __restrict__ kh,
                 const bf16_t* __restrict__ vT, bf16_t* __restrict__ O)
{
    __shared__ bf16x8 lK[64 * 8];      // [krow][dh-chunk], swizzled
    __shared__ bf16x8 lV[64 * 8];      // [dh][kcol-chunk], swizzled
    __shared__ bf16x8 lP8[8][128];     // per-wave P tile [16 q][64 kv] bf16, swizzled
    const int tid = threadIdx.x, wid = tid >> 6, lane = tid & 63;
    const int lr = lane & 15, lh = lane >> 4;
    const int bh = blockIdx.x & 63;          // xcd = bid%8 = bh%8: q-tiles of one bh share XCD
    const int p  = blockIdx.x >> 6;          // 0..7
    const bf16_t* Qp = qh + (size_t)bh * S_ * DH_;
    const bf16_t* Kp = kh + (size_t)bh * S_ * DH_;
    const bf16_t* Vp = vT + (size_t)bh * DH_ * S_;
    char* lP = (char*)lP8[wid];
    const int b = bh >> 4, h = bh & 15;
    const float QSCALE = 0.125f * 1.44269504f;   // 1/sqrt(DH) * log2(e)

    #pragma unroll 1
    for (int ph = 0; ph < 2; ++ph) {
        const int q0 = (ph == 0 ? (15 - p) : p) * 128;
        const int wq = q0 + wid * 16;

        // Q fragments (B-operand of S^T), pre-scaled into log2 domain
        bf16x8 qf[2];
        #pragma unroll
        for (int ks = 0; ks < 2; ++ks) {
            bf16x8 t = *(const bf16x8*)(Qp + (size_t)(wq + lr) * DH_ + ks * 32 + lh * 8);
            #pragma unroll
            for (int e = 0; e < 8; ++e) t[e] = (__bf16)((float)t[e] * QSCALE);
            qf[ks] = t;
        }

        f32x4 accO[4] = {};
        float mrun = -1e30f, lrun = 0.f;
        const int nkt = q0 / 64 + 2;

        #pragma unroll 1
        for (int kt = 0; kt < nkt; ++kt) {
            __syncthreads();
            {   // K/V tile staging via global_load_lds: wave wid stages slots [wid*64, +64)
                int slot = (wid << 6) + lane;
                int row = slot >> 3, s = slot & 7, c = s ^ (row & 7);
                glds16(Kp + (size_t)(kt * 64 + row) * DH_ + c * 8, &lK[wid << 6]);
                glds16(Vp + (size_t)row * S_ + kt * 64 + c * 8, &lV[wid << 6]);
            }
            __syncthreads();

            if (kt * 64 > wq + 15) continue;   // fully-masked tile for this wave

            // S^T = K.Q^T : sc[kvi], kv row = 16*kvi + 4*lh + j, q col = lr
            f32x4 sc[4] = {};
            __builtin_amdgcn_s_setprio(1);
            #pragma unroll
            for (int ks = 0; ks < 2; ++ks) {
                int kh8 = ks * 4 + lh;
                #pragma unroll
                for (int kvi = 0; kvi < 4; ++kvi) {
                    int r = kvi * 16 + lr;
                    bf16x8 kf = lK[r * 8 + (kh8 ^ (r & 7))];
                    sc[kvi] = mfma16(kf, qf[ks], sc[kvi]);
                }
            }
            __builtin_amdgcn_s_setprio(0);

            const bool needm = (kt * 64 + 63 > wq);
            const int kvb = kt * 64 + 4 * lh;
            const int qg = wq + lr;
            float pv[16];
            #pragma unroll
            for (int kvi = 0; kvi < 4; ++kvi)
                #pragma unroll
                for (int j = 0; j < 4; ++j) {
                    float x = sc[kvi][j];
                    if (needm && (kvb + kvi * 16 + j) > qg) x = -1e30f;
                    pv[kvi * 4 + j] = x;
                }
            // row max: in-lane tree + cross-group
            float m8[8], m4v[4];
            #pragma unroll
            for (int i = 0; i < 8; ++i) m8[i] = fmaxf(pv[i], pv[i + 8]);
            #pragma unroll
            for (int i = 0; i < 4; ++i) m4v[i] = fmaxf(m8[i], m8[i + 4]);
            float mx = fmaxf(fmaxf(m4v[0], m4v[2]), fmaxf(m4v[1], m4v[3]));
            mx = fmaxf(mx, __shfl_xor(mx, 16));
            mx = fmaxf(mx, __shfl_xor(mx, 32));

            float mnew;
            float rs = 1.f;
            bool skip = __all(mx <= mrun + 8.0f);   // defer-max: P bounded by 2^8
            if (skip) {
                mnew = mrun;
            } else {
                mnew = fmaxf(mrun, mx);
                rs = fast_exp2(mrun - mnew);
                mrun = mnew;
            }
            // exp2 + sum
            #pragma unroll
            for (int i = 0; i < 16; ++i) pv[i] = fast_exp2(pv[i] - mnew);
            float s8[8], s4v[4];
            #pragma unroll
            for (int i = 0; i < 8; ++i) s8[i] = pv[i] + pv[i + 8];
            #pragma unroll
            for (int i = 0; i < 4; ++i) s4v[i] = s8[i] + s8[i + 4];
            float sum = (s4v[0] + s4v[1]) + (s4v[2] + s4v[3]);
            sum += __shfl_xor(sum, 16);
            sum += __shfl_xor(sum, 32);

            // write P[q][kv] to per-wave LDS: 8B per kvi, 16B-slot XOR swizzle
            #pragma unroll
            for (int kvi = 0; kvi < 4; ++kvi) {
                bf16x4 hv = { (__bf16)pv[kvi * 4 + 0], (__bf16)pv[kvi * 4 + 1],
                              (__bf16)pv[kvi * 4 + 2], (__bf16)pv[kvi * 4 + 3] };
                int slot = 2 * kvi + (lh >> 1);
                *(bf16x4*)(lP + lr * 128 + ((slot ^ (lr & 7)) * 16) + (lh & 1) * 8) = hv;
            }

            if (skip) {
                lrun += sum;
            } else {
                lrun = lrun * rs + sum;
                // rescale accO rows q = 4*lh + j: state lives at lane (4*lh + j)
                #pragma unroll
                for (int j = 0; j < 4; ++j) {
                    float rj = __shfl(rs, 4 * lh + j);
                    #pragma unroll
                    for (int ni = 0; ni < 4; ++ni) accO[ni][j] *= rj;
                }
            }

            // PV: O += P @ V  (A = P from per-wave LDS, B = V^T tile)
            __builtin_amdgcn_s_setprio(1);
            #pragma unroll
            for (int ks = 0; ks < 2; ++ks) {
                int kh8 = ks * 4 + lh;
                int slot = 4 * ks + lh;
                bf16x8 pf = *(const bf16x8*)(lP + lr * 128 + ((slot ^ (lr & 7)) * 16));
                #pragma unroll
                for (int ni = 0; ni < 4; ++ni) {
                    int r = ni * 16 + lr;
                    bf16x8 vf = lV[r * 8 + (kh8 ^ (r & 7))];
                    accO[ni] = mfma16(pf, vf, accO[ni]);
                }
            }
            __builtin_amdgcn_s_setprio(0);
        }

        // epilogue: rows q = 4*lh + j, col dh = ni*16 + lr
        #pragma unroll
        for (int j = 0; j < 4; ++j) {
            int s = wq + 4 * lh + j;
            float inv = 1.f / __shfl(lrun, 4 * lh + j);
            #pragma unroll
            for (int ni = 0; ni < 4; ++ni) {
                int dh = ni * 16 + lr;
                O[((size_t)(b * S_ + s)) * D_ + h * DH_ + dh] = (bf16_t)(accO[ni][j] * inv);
            }
        }
    }
}

// ---------------- Output GEMM: out(f32) = O(bf16) @ Wo^T(bf16) ----------------------
__global__ __launch_bounds__(256)
void out_kernel(const bf16_t* __restrict__ A, const bf16_t* __restrict__ W,
                float* __restrict__ out)
{
    __shared__ bf16x8 lA[128 * 8];
    __shared__ bf16x8 lB[128 * 8];
    const int tid = threadIdx.x;
    const int gm0 = blockIdx.x * 128;
    const int gn0 = blockIdx.y * 128;
    const int wid = tid >> 6, lane = tid & 63;
    const int lr = lane & 15, lh = lane >> 4;
    const int wm = (wid >> 1) * 64, wn = (wid & 1) * 64;

    f32x4 acc[4][4] = {};

    for (int kt = 0; kt < D_ / 64; ++kt) {
        const int k0 = kt * 64;
        __syncthreads();
        #pragma unroll
        for (int i = 0; i < 4; ++i) {
            int base = wid * 64 + i * 256;
            int slot = base + lane;
            int row = slot >> 3, s = slot & 7, c = s ^ (row & 7);
            glds16(A + (size_t)(gm0 + row) * D_ + k0 + c * 8, &lA[base]);
            glds16(W + (size_t)(gn0 + row) * D_ + k0 + c * 8, &lB[base]);
        }
        __syncthreads();
        #pragma unroll
        for (int ks = 0; ks < 2; ++ks) {
            bf16x8 af[4], bfr[4];
            int kh = ks * 4 + lh;
            #pragma unroll
            for (int mi = 0; mi < 4; ++mi) { int r = wm + mi * 16 + lr; af[mi]  = lA[r * 8 + (kh ^ (r & 7))]; }
            #pragma unroll
            for (int ni = 0; ni < 4; ++ni) { int r = wn + ni * 16 + lr; bfr[ni] = lB[r * 8 + (kh ^ (r & 7))]; }
            #pragma unroll
            for (int mi = 0; mi < 4; ++mi)
                #pragma unroll
                for (int ni = 0; ni < 4; ++ni)
                    acc[mi][ni] = mfma16(af[mi], bfr[ni], acc[mi][ni]);
        }
    }

    #pragma unroll
    for (int mi = 0; mi < 4; ++mi)
        #pragma unroll
        for (int j = 0; j < 4; ++j) {
            int m = gm0 + wm + mi * 16 + lh * 4 + j;
            #pragma unroll
            for (int ni = 0; ni < 4; ++ni) {
                int n = gn0 + wn + ni * 16 + lr;
                out[(size_t)m * D_ + n] = acc[mi][ni][j];
            }
        }
}

extern "C" void kernel_launch(void* const* d_in, const int* in_sizes, int n_in,
                              void* d_out, int out_size, void* d_ws, size_t ws_size,
                              hipStream_t stream)
{
    const float* Q  = (const float*)d_in[0];
    const float* K  = (const float*)d_in[1];
    const float* V  = (const float*)d_in[2];
    const float* Wq = (const float*)d_in[3];
    const float* Wk = (const float*)d_in[4];
    const float* Wv = (const float*)d_in[5];
    const float* Wo = (const float*)d_in[6];
    float* out = (float*)d_out;

    char* ws = (char*)d_ws;
    const size_t MB = 1024 * 1024;
    bf16_t* Xbf = (bf16_t*)(ws);                // region0: X bf16 (per-proj) then Ob, 16 MB
    bf16_t* Ob  = (bf16_t*)(ws);                // alias: attn output [B*S][D] bf16
    bf16_t* qh  = (bf16_t*)(ws + 16 * MB);      // [B][H][S][DH] bf16, 16 MB
    bf16_t* khb = (bf16_t*)(ws + 32 * MB);      // [B][H][S][DH] bf16, 16 MB
    bf16_t* vT  = (bf16_t*)(ws + 48 * MB);      // [B][H][DH][S] bf16, 16 MB
    bf16_t* Wb  = (bf16_t*)(ws + 64 * MB);      // 4 x [1024*1024] bf16, 8 MB
    float2* tab = (float2*)(ws + 72 * MB);      // [S][32] (sin,cos), 512 KB

    rope_table_kernel<<<S_ * 32 / 256, 256, 0, stream>>>(tab);
    wcvt_kernel<<<2048, 256, 0, stream>>>(Wq, Wk, Wv, Wo, Wb);

    dim3 g(64, 8);
    const int XBLK = (B_ * S_ * D_) / 8 / 256;  // 4096

    cvt_kernel<<<XBLK, 256, 0, stream>>>(Q, Xbf);
    proj_kernel<0><<<g, 256, 0, stream>>>(Xbf, Wb + 0 * 1048576, qh, tab);
    cvt_kernel<<<XBLK, 256, 0, stream>>>(K, Xbf);
    proj_kernel<0><<<g, 256, 0, stream>>>(Xbf, Wb + 1 * 1048576, khb, tab);
    cvt_kernel<<<XBLK, 256, 0, stream>>>(V, Xbf);
    proj_kernel<1><<<g, 256, 0, stream>>>(Xbf, Wb + 2 * 1048576, vT, tab);

    attn_kernel<<<512, 512, 0, stream>>>(qh, khb, vT, Ob);

    out_kernel<<<g, 256, 0, stream>>>(Ob, Wb + 3 * 1048576, out);
}